// Round 10
// baseline (88.825 us; speedup 1.0000x reference)
//
#include <hip/hip_runtime.h>
#include <hip/hip_bf16.h>

#define NHEADS 6
#define HD 32
#define CDIM 192
#define NTOK 64
#define NREL 225
#define PDIM 12
#define IMG 256
#define NWIN 2048
#define QSCALE 0.2550348686f      // 32^-0.5 * log2(e)
#define LOG2E 1.4426950408889634f

typedef __attribute__((ext_vector_type(8))) short v8s;
typedef __attribute__((ext_vector_type(4))) float v4f;

#define KS2 200  // ks row stride (ushort): 400B
#define VTS 72   // vt row stride: 144B
#define PTS 72   // pt row stride: 144B

__device__ __forceinline__ unsigned pkbf(float x, float y) {
    __hip_bfloat162 h = __float22bfloat162_rn(make_float2(x, y));
    union { __hip_bfloat162 h; unsigned u; } c; c.h = h;
    return c.u;
}

// v_exp_f32: D = 2^x (pure, schedulable)
__device__ __forceinline__ float ex2(float x) {
    float r; asm("v_exp_f32 %0, %1" : "=v"(r) : "v"(x)); return r;
}

__device__ __forceinline__ void ln_relu12(const float* x, const float* g,
                                          const float* be, float* y) {
    float m = 0.f;
#pragma unroll
    for (int i = 0; i < PDIM; ++i) m += x[i];
    m *= (1.f / PDIM);
    float v = 0.f;
#pragma unroll
    for (int i = 0; i < PDIM; ++i) { float d = x[i] - m; v += d * d; }
    v *= (1.f / PDIM);
    float inv = rsqrtf(v + 1e-5f);
#pragma unroll
    for (int i = 0; i < PDIM; ++i) {
        float t = (x[i] - m) * inv * g[i] + be[i];
        y[i] = t > 0.f ? t : 0.f;
    }
}

__global__ __launch_bounds__(512, 4) void win_attn_fused(
    const float* __restrict__ qkv,
    const float* __restrict__ wp, const float* __restrict__ bp,
    const float* __restrict__ g1, const float* __restrict__ be1,
    const float* __restrict__ w1, const float* __restrict__ b1,
    const float* __restrict__ g2, const float* __restrict__ be2,
    const float* __restrict__ w2, const float* __restrict__ b2,
    const float* __restrict__ g3, const float* __restrict__ be3,
    const float* __restrict__ w3, const float* __restrict__ b3,
    float* __restrict__ out)
{
    __shared__ __align__(16) unsigned short ks[NTOK * KS2];     // K, all heads
    __shared__ __align__(16) unsigned short vt[CDIM * VTS];     // V^T
    __shared__ __align__(16) unsigned short pt[2][NTOK * PTS];  // P per head-half
    __shared__ __align__(16) float pshf[NREL * 8];              // bias [idx][8], swizzled

    const int t = threadIdx.x;
    const int win = blockIdx.x;
    const int b  = win >> 10;
    const int bh = (win >> 5) & 31;
    const int bw = win & 31;

    const int lane = t & 63;
    const int wave = t >> 6;          // 0..7
    const int rg   = wave & 3;
    const int hh   = wave >> 2;       // 0: heads 0-2, 1: heads 3-5
    const int hbase = hh * 3;
    const int lw = lane & 15;
    const int lg = lane >> 4;
    const int rowbase = rg * 16;

    const size_t PL = (size_t)2 * IMG * IMG * CDIM;
    const float* qplane = qkv + (size_t)b * IMG * IMG * CDIM;
    const float* kplane = qplane + PL;
    const float* vplane = kplane + PL;

    auto pixoff = [&](int tok) -> size_t {
        return ((size_t)(bh * 8 + (tok >> 3)) * IMG + (bw * 8 + (tok & 7))) * CDIM;
    };

    // ---------- K: fully contiguous streaming ----------
#pragma unroll
    for (int pass = 0; pass < 6; ++pass) {
        int fidx = t + pass * 512;            // 0..3071
        int s   = fidx / 384;
        int rem = fidx - s * 384;
        int j1  = rem / 48;
        int f   = rem - j1 * 48;
        float4 k4 = *(const float4*)(kplane
                     + ((size_t)(bh * 8 + s) * IMG + (bw * 8 + j1)) * CDIM + f * 4);
        uint2 kk; kk.x = pkbf(k4.x, k4.y); kk.y = pkbf(k4.z, k4.w);
        *(uint2*)&ks[(s * 8 + j1) * KS2 + f * 4] = kk;
    }

    // ---------- V: k'-paired transpose, 3 heads per thread ----------
    {
        const int u  = t & 31;
        const int dg = (t >> 5) & 7;
        const int vh = t >> 8;
        const int ta = (u & 15) + (u >> 4) * 32;
        const int db = dg * 4;
        const int kpa = (u & 15) * 4 + (u >> 4) * 2;
        const size_t offa = pixoff(ta), offb = pixoff(ta + 16);
#pragma unroll
        for (int hi = 0; hi < 3; ++hi) {
            int h = vh * 3 + hi;
            float4 va = *(const float4*)(vplane + offa + h * HD + db);
            float4 vb = *(const float4*)(vplane + offb + h * HD + db);
            int row = h * HD + db;
            *(unsigned*)&vt[(row + 0) * VTS + kpa] = pkbf(va.x, vb.x);
            *(unsigned*)&vt[(row + 1) * VTS + kpa] = pkbf(va.y, vb.y);
            *(unsigned*)&vt[(row + 2) * VTS + kpa] = pkbf(va.z, vb.z);
            *(unsigned*)&vt[(row + 3) * VTS + kpa] = pkbf(va.w, vb.w);
        }
    }

    // ---------- Q: this wave's 3 heads, pre-scaled by SCALE*log2e ----------
    v8s aq[3];
    {
        const size_t qoff = pixoff(rowbase + lw);
#pragma unroll
        for (int hi = 0; hi < 3; ++hi) {
            const float* qp = qplane + qoff + (hbase + hi) * HD + lg * 8;
            float4 q0 = *(const float4*)qp;
            float4 q1 = *(const float4*)(qp + 4);
            union { v8s v; unsigned x[4]; } au;
            au.x[0] = pkbf(q0.x * QSCALE, q0.y * QSCALE);
            au.x[1] = pkbf(q0.z * QSCALE, q0.w * QSCALE);
            au.x[2] = pkbf(q1.x * QSCALE, q1.y * QSCALE);
            au.x[3] = pkbf(q1.z * QSCALE, q1.w * QSCALE);
            aq[hi] = au.v;
        }
    }

    // ---------- fused MLP: bias * log2e, layout [idx][8] XOR-swizzled ----------
    if (t < NREL) {
        float x0 = (float)(t / 15 - 7);
        float x1 = (float)(t % 15 - 7);
        float h[PDIM], y[PDIM];
#pragma unroll
        for (int o = 0; o < PDIM; ++o)
            h[o] = x0 * wp[o] + x1 * wp[PDIM + o] + bp[o];
        ln_relu12(h, g1, be1, y);
#pragma unroll
        for (int o = 0; o < PDIM; ++o) {
            float a = b1[o];
#pragma unroll
            for (int i = 0; i < PDIM; ++i) a += y[i] * w1[i * PDIM + o];
            h[o] = a;
        }
        ln_relu12(h, g2, be2, y);
#pragma unroll
        for (int o = 0; o < PDIM; ++o) {
            float a = b2[o];
#pragma unroll
            for (int i = 0; i < PDIM; ++i) a += y[i] * w2[i * PDIM + o];
            h[o] = a;
        }
        ln_relu12(h, g3, be3, y);
        const int sw = (t >> 2) & 1;
#pragma unroll
        for (int o = 0; o < NHEADS; ++o) {
            float a = b3[o];
#pragma unroll
            for (int i = 0; i < PDIM; ++i) a += y[i] * w3[i * NHEADS + o];
            int half = (o >= 3) ? 1 : 0;
            pshf[(t * 2 + (half ^ sw)) * 4 + (o - half * 3)] = a * LOG2E;
        }
    }
    __syncthreads();   // ks, vt, pshf visible; only barrier

    // ---------- per-row constants ----------
    int base_r[4];
#pragma unroll
    for (int r = 0; r < 4; ++r) {
        int n = rowbase + lg * 4 + r;
        base_r[r] = ((n >> 3) - (lw >> 3) + 7) * 15 + (n & 7) - (lw & 7) + 7;
    }

    // ---------- phase 1: 12 independent QK MFMAs ----------
    v4f acc[3][4];   // [head][ct]
#pragma unroll
    for (int ct = 0; ct < 4; ++ct) {
#pragma unroll
        for (int hi = 0; hi < 3; ++hi) {
            v4f z = {0.f, 0.f, 0.f, 0.f};
            v8s bfr = *(const v8s*)&ks[(ct * 16 + lw) * KS2 + (hbase + hi) * HD + lg * 8];
            acc[hi][ct] = __builtin_amdgcn_mfma_f32_16x16x32_bf16(aq[hi], bfr, z, 0, 0, 0);
        }
    }

    // ---------- phase 2: shared b128 bias + exp2 (3 heads per load) ----------
#pragma unroll
    for (int ct = 0; ct < 4; ++ct)
#pragma unroll
        for (int r = 0; r < 4; ++r) {
            int idx = base_r[r] - ct * 30;
            const float4 bb = *(const float4*)&pshf[(idx * 2 + (hh ^ ((idx >> 2) & 1))) * 4];
            acc[0][ct][r] = ex2(acc[0][ct][r] + bb.x);
            acc[1][ct][r] = ex2(acc[1][ct][r] + bb.y);
            acc[2][ct][r] = ex2(acc[2][ct][r] + bb.z);
        }

    // ---------- per-row output offsets ----------
    size_t ooff[4];
#pragma unroll
    for (int r = 0; r < 4; ++r) {
        int n = rowbase + lg * 4 + r;
        ooff[r] = ((size_t)(b * IMG + bh * 8 + (n >> 3)) * IMG
                   + (bw * 8 + (n & 7))) * CDIM;
    }

    // ones B-fragment for the sum-MFMA (bf16 1.0 = 0x3F80)
    v8s ones;
#pragma unroll
    for (int j = 0; j < 8; ++j) ones[j] = (short)0x3F80;

    // ---------- phase 3: per head {P store, PV + sum MFMA, out} ----------
#pragma unroll
    for (int hi = 0; hi < 3; ++hi) {
        const int h = hbase + hi;
        // P store (k'-packed b64; wave-private rows)
#pragma unroll
        for (int r = 0; r < 4; ++r) {
            uint2 w;
            w.x = pkbf(acc[hi][0][r], acc[hi][1][r]);
            w.y = pkbf(acc[hi][2][r], acc[hi][3][r]);
            *(uint2*)&pt[hh][(rowbase + lg * 4 + r) * PTS + lw * 4] = w;
        }
        v8s pa[2];
#pragma unroll
        for (int kt = 0; kt < 2; ++kt)
            pa[kt] = *(const v8s*)&pt[hh][(rowbase + lw) * PTS + kt * 32 + lg * 8];
        // O_unnorm = P V ; rowsum = P * ones
        v4f acc2[2] = {};
        v4f acc3 = {0.f, 0.f, 0.f, 0.f};
#pragma unroll
        for (int kt = 0; kt < 2; ++kt) {
#pragma unroll
            for (int dt = 0; dt < 2; ++dt) {
                v8s vb = *(const v8s*)&vt[(h * HD + dt * 16 + lw) * VTS
                                          + kt * 32 + lg * 8];
                acc2[dt] = __builtin_amdgcn_mfma_f32_16x16x32_bf16(pa[kt], vb, acc2[dt], 0, 0, 0);
            }
            acc3 = __builtin_amdgcn_mfma_f32_16x16x32_bf16(pa[kt], ones, acc3, 0, 0, 0);
        }
        v4f rinv;
#pragma unroll
        for (int r = 0; r < 4; ++r) rinv[r] = __builtin_amdgcn_rcpf(acc3[r]);
#pragma unroll
        for (int dt = 0; dt < 2; ++dt)
#pragma unroll
            for (int r = 0; r < 4; ++r)
                out[ooff[r] + h * HD + dt * 16 + lw] = acc2[dt][r] * rinv[r];
    }
}

extern "C" void kernel_launch(void* const* d_in, const int* in_sizes, int n_in,
                              void* d_out, int out_size, void* d_ws, size_t ws_size,
                              hipStream_t stream) {
    const float* qkv = (const float*)d_in[0];
    win_attn_fused<<<NWIN, 512, 0, stream>>>(
        qkv,
        (const float*)d_in[1], (const float*)d_in[2],
        (const float*)d_in[3], (const float*)d_in[4],
        (const float*)d_in[5], (const float*)d_in[6],
        (const float*)d_in[7], (const float*)d_in[8],
        (const float*)d_in[9], (const float*)d_in[10],
        (const float*)d_in[11], (const float*)d_in[12],
        (const float*)d_in[13], (const float*)d_in[14],
        (float*)d_out);
}